// Round 14
// baseline (492.266 us; speedup 1.0000x reference)
//
#include <hip/hip_runtime.h>
#include <hip/hip_bf16.h>
#include <math.h>

constexpr int Bc = 2, Sc = 2048, Dc = 1024, Hc = 16, HDc = 64;
constexpr int D3 = 3 * Dc;

typedef __bf16 bf16x8 __attribute__((ext_vector_type(8)));
typedef float f32x4 __attribute__((ext_vector_type(4)));

__device__ __forceinline__ void gll16(const void* g, void* l) {
  __builtin_amdgcn_global_load_lds((const __attribute__((address_space(1))) unsigned int*)g,
                                   (__attribute__((address_space(3))) unsigned int*)l,
                                   16, 0, 0);
}

__device__ __forceinline__ unsigned short f2bf(float v) {
  __hip_bfloat16 h = __float2bfloat16(v);
  return *(unsigned short*)&h;
}
__device__ __forceinline__ float b2f(unsigned short u) {
  unsigned v = ((unsigned)u) << 16;
  return __uint_as_float(v);
}

#define SBAR() asm volatile("s_barrier" ::: "memory")

// ---------------- Householder product Q (64x64), 1 block, 64 threads ----------------
__global__ __launch_bounds__(64) void hh_kernel(const float* __restrict__ vs,
                                                float* __restrict__ Qout) {
  __shared__ float Qm[64][65];
  __shared__ float vsh[64];
  int t = threadIdx.x;
  for (int i = 0; i < 64; ++i) Qm[i][t] = (i == t) ? 1.0f : 0.0f;
  for (int it = 0; it < 32; ++it) {
    __syncthreads();
    vsh[t] = vs[it * 64 + t];
    __syncthreads();
    float nv = 0.0f;
    for (int i = 0; i < 64; ++i) nv += vsh[i] * vsh[i];
    float c = 2.0f / (nv + 1e-8f);
    float wj = 0.0f;
    for (int i = 0; i < 64; ++i) wj += vsh[i] * Qm[i][t];
    for (int i = 0; i < 64; ++i) Qm[i][t] -= c * vsh[i] * wj;
  }
  __syncthreads();
  for (int i = 0; i < 64; ++i) Qout[i * 64 + t] = Qm[i][t];
}

// ---------------- RMSNorm body ----------------
__device__ __forceinline__ void rms_body(const float* __restrict__ in,
                                         unsigned short* __restrict__ out, int row, int t) {
  const float4* x4 = (const float4*)(in + (size_t)row * Dc);
  float4 v = x4[t];
  float s = v.x * v.x + v.y * v.y + v.z * v.z + v.w * v.w;
#pragma unroll
  for (int off = 1; off < 64; off <<= 1) s += __shfl_xor(s, off);
  __shared__ float wsum[4];
  if ((t & 63) == 0) wsum[t >> 6] = s;
  __syncthreads();
  float tot = wsum[0] + wsum[1] + wsum[2] + wsum[3];
  float r = rsqrtf(tot * (1.0f / Dc) + 1.1920928955078125e-07f);
  ushort4 o;
  o.x = f2bf(v.x * r); o.y = f2bf(v.y * r); o.z = f2bf(v.z * r); o.w = f2bf(v.w * r);
  ((ushort4*)(out + (size_t)row * Dc))[t] = o;
}

__global__ __launch_bounds__(256) void rmsnorm_bf16_kernel(const float* __restrict__ in,
                                                           unsigned short* __restrict__ out) {
  rms_body(in, out, blockIdx.x, threadIdx.x);
}

// ---------------- merged prep (R13b: only pre-QKV work; weight casts moved to mattn) --
//   [0,256)      rtab
//   [256,512)    wqk2 (LDS-staged Qm, W read once)
//   [512,1536)   f2b qkv_w v-part (needed by the QKV GEMM)
//   [1536,5632)  rmsnorm(x) rows (independent; rides prep's tail)
__global__ __launch_bounds__(256) void prep_kernel(const float* __restrict__ qkv_w,
                                                   const float* __restrict__ rope_pos,
                                                   const float* __restrict__ inv_freq,
                                                   const float* __restrict__ Qm,
                                                   const float* __restrict__ x,
                                                   float2* __restrict__ rtab,
                                                   unsigned short* __restrict__ wqkvb,
                                                   unsigned short* __restrict__ xn) {
  const int blk = blockIdx.x;
  const int t = threadIdx.x;
  if (blk < 256) {
    int id = blk * 256 + t;  // 65536 = 2048*32
    int s = id >> 5, d = id & 31;
    float pos = rope_pos[s * 2 + (d >> 4)];
    float emb = pos * inv_freq[d & 15];
    rtab[id] = make_float2(cosf(emb), sinf(emb));
  } else if (blk < 512) {
    __shared__ float qs[64 * 64];  // 16 KB
    const int gid = blk - 256;     // 0..255
    const int g = gid >> 3;
    const int c = gid & 7;
    const int base = g * 64;
#pragma unroll
    for (int i = 0; i < 16; ++i) qs[t + i * 256] = Qm[t + i * 256];
    __syncthreads();
    const int tj = t & 127;
    const int rh = (t >> 7) * 32;
    const int col = c * 128 + tj;
    float acc[32] = {};
    const float* wp = qkv_w + (size_t)base * 1024 + col;
    for (int e = 0; e < 64; ++e) {
      float wv = wp[(size_t)e * 1024];
#pragma unroll
      for (int r = 0; r < 32; ++r) acc[r] += qs[(rh + r) * 64 + e] * wv;
    }
    const float sc = (base < 1024) ? 0.18033688f : 1.0f;  // 0.125 * log2(e)
#pragma unroll
    for (int r = 0; r < 32; ++r)
      wqkvb[(size_t)(base + rh + r) * 1024 + col] = f2bf(acc[r] * sc);
  } else if (blk < 1536) {
    int i = (blk - 512) * 256 + t;
    float4 v = ((const float4*)(qkv_w + (size_t)2048 * 1024))[i];
    ushort4 o;
    o.x = f2bf(v.x); o.y = f2bf(v.y); o.z = f2bf(v.z); o.w = f2bf(v.w);
    ((ushort4*)(wqkvb + (size_t)2048 * 1024))[i] = o;
  } else {
    rms_body(x, xn, blk - 1536, t);
  }
}

// ---------------- merged RoPE-rotate + V-transpose (both read qkvb) ----------------
__global__ __launch_bounds__(256) void ropevt_kernel(const unsigned short* __restrict__ qkv,
                                                     const float2* __restrict__ tab,
                                                     unsigned short* __restrict__ qb,
                                                     unsigned short* __restrict__ kb,
                                                     unsigned short* __restrict__ vtb) {
  __shared__ unsigned short tile[64 * 72];
  const int blk = blockIdx.x;
  const int t = threadIdx.x;
  if (blk < 2048) {
    int gid = blk * 64 + (t >> 2);
    int sub = t & 3;
    int h = gid & 15;
    int which = (gid >> 4) & 1;
    int tok = gid >> 5;
    int s = tok & (Sc - 1), b = tok >> 11;
    const unsigned short* src = qkv + (size_t)tok * D3 + which * Dc + h * 64 + sub * 8;
    uint4 lov = *(const uint4*)src;
    uint4 hiv = *(const uint4*)(src + 32);
    const unsigned short* lp = (const unsigned short*)&lov;
    const unsigned short* hp = (const unsigned short*)&hiv;
    unsigned short olo[8], ohi[8];
    const float2* tp = tab + s * 32 + sub * 8;
#pragma unroll
    for (int i = 0; i < 8; ++i) {
      float2 cs = tp[i];
      float lo = b2f(lp[i]), hi = b2f(hp[i]);
      olo[i] = f2bf(lo * cs.x - hi * cs.y);
      ohi[i] = f2bf(hi * cs.x + lo * cs.y);
    }
    unsigned short* dst = (which ? kb : qb) + ((size_t)((b * Hc + h) * Sc + s)) * 64 + sub * 8;
    *(uint4*)dst = *(uint4*)olo;
    *(uint4*)(dst + 32) = *(uint4*)ohi;
  } else {
    int v = blk - 2048;
    int st = v & 31;
    int bh = v >> 5;
    int b = bh >> 4, h = bh & 15;
    int srow = t >> 2, c16 = (t & 3) * 16;
    const unsigned short* src =
        qkv + (size_t)(b * Sc + st * 64 + srow) * D3 + 2 * Dc + h * 64 + c16;
    uint4 a0 = *(const uint4*)src;
    uint4 a1 = *(const uint4*)(src + 8);
    *(uint4*)(tile + srow * 72 + c16) = a0;
    *(uint4*)(tile + srow * 72 + c16 + 8) = a1;
    __syncthreads();
    int d = t >> 2, sch = (t & 3) * 16;
    unsigned short tmp[16];
#pragma unroll
    for (int i = 0; i < 16; ++i) tmp[i] = tile[(sch + i) * 72 + d];
    unsigned short* dst = vtb + ((size_t)(bh * 64 + d)) * Sc + st * 64 + sch;
    *(uint4*)dst = *(uint4*)tmp;
    *(uint4*)(dst + 8) = *(uint4*)(tmp + 8);
  }
}

// ---------------- 256x256 8-phase bf16 MFMA GEMM (T1+T2+T3+T4+T5) ----------------
// At/above the m248-measured structure ceiling for K=1024 (910 vs 848 TF) -- unchanged.
// MODE 0: C[m][n] = f2bf(acc)             (stride N)
// MODE 1: B is w12-interleaved; C[m][col] = silu(x1)*x2, stride N/2.
template <int MODE>
__global__ __launch_bounds__(512, 1) void mgemm8p(const unsigned short* __restrict__ A,
                                                  const unsigned short* __restrict__ B,
                                                  unsigned short* __restrict__ C,
                                                  int M, int N, int K) {
  __shared__ unsigned short lds[65536];
  const int t = threadIdx.x;
  const int lane = t & 63;
  const int wave = t >> 6;
  const int wr = wave >> 2, wc = wave & 3;
  const int l15 = lane & 15, l4 = lane >> 4;
  const int gx = gridDim.x;
  const int nwg = gx * gridDim.y;
  const int id = blockIdx.y * gx + blockIdx.x;
  const int swz = (id & 7) * (nwg >> 3) + (id >> 3);
  const int m0 = (swz / gx) * 256;
  const int n0 = (swz % gx) * 256;
  const int NT = K >> 6;
  const int sko = (((t & 3) ^ ((t >> 3) & 3)) * 8);
  const unsigned short* ag0 = A + (size_t)(m0 + (t >> 2)) * K + sko;
  const unsigned short* ag1 = ag0 + (size_t)128 * K;
  const unsigned short* bg0 = B + (size_t)(n0 + (t >> 2)) * K + sko;
  const unsigned short* bg1 = bg0 + (size_t)128 * K;
  const int t8 = t * 8;
  const int ks = (l4 ^ ((l15 >> 1) & 3)) * 8;
  gll16(ag0, lds + t8);
  gll16(ag1, lds + 4096 + t8);
  gll16(bg0, lds + 32768 + t8);
  gll16(bg1, lds + 32768 + 4096 + t8);
  gll16(ag0 + 32, lds + 8192 + t8);
  gll16(ag1 + 32, lds + 8192 + 4096 + t8);
  gll16(bg0 + 32, lds + 32768 + 8192 + t8);
  gll16(bg1 + 32, lds + 32768 + 8192 + 4096 + t8);
  asm volatile("s_waitcnt vmcnt(4)" ::: "memory");
  SBAR();
  f32x4 acc[8][4] = {};
  for (int kt = 0; kt < NT; ++kt) {
    const int cur = (kt & 1) << 14;
    const int nxt = cur ^ 16384;
    const int kof = ((kt + 1 < NT) ? (kt + 1) : kt) << 6;
    const unsigned short* Ap = lds + cur;
    const unsigned short* Bp = lds + 32768 + cur;
    bf16x8 a[8], b0, b1;
    // ---- phase 1: kh0 x Nfrags {0,1} ----
#pragma unroll
    for (int i = 0; i < 8; ++i)
      a[i] = *(const bf16x8*)(Ap + (wr * 128 + i * 16 + l15) * 32 + ks);
    b0 = *(const bf16x8*)(Bp + (wc * 64 + l15) * 32 + ks);
    b1 = *(const bf16x8*)(Bp + (wc * 64 + 16 + l15) * 32 + ks);
    gll16(ag0 + kof, lds + nxt + t8);
    gll16(ag1 + kof, lds + nxt + 4096 + t8);
    SBAR();
    __builtin_amdgcn_s_setprio(1);
#pragma unroll
    for (int i = 0; i < 8; ++i) {
      acc[i][0] = __builtin_amdgcn_mfma_f32_16x16x32_bf16(a[i], b0, acc[i][0], 0, 0, 0);
      acc[i][1] = __builtin_amdgcn_mfma_f32_16x16x32_bf16(a[i], b1, acc[i][1], 0, 0, 0);
    }
    __builtin_amdgcn_s_setprio(0);
    SBAR();
    // ---- phase 2: kh0 x Nfrags {2,3} ----
    b0 = *(const bf16x8*)(Bp + (wc * 64 + 32 + l15) * 32 + ks);
    b1 = *(const bf16x8*)(Bp + (wc * 64 + 48 + l15) * 32 + ks);
    gll16(bg0 + kof, lds + 32768 + nxt + t8);
    gll16(bg1 + kof, lds + 32768 + nxt + 4096 + t8);
    asm volatile("s_waitcnt vmcnt(4)" ::: "memory");
    SBAR();
    __builtin_amdgcn_s_setprio(1);
#pragma unroll
    for (int i = 0; i < 8; ++i) {
      acc[i][2] = __builtin_amdgcn_mfma_f32_16x16x32_bf16(a[i], b0, acc[i][2], 0, 0, 0);
      acc[i][3] = __builtin_amdgcn_mfma_f32_16x16x32_bf16(a[i], b1, acc[i][3], 0, 0, 0);
    }
    __builtin_amdgcn_s_setprio(0);
    SBAR();
    // ---- phase 3: kh1 x Nfrags {0,1} ----
#pragma unroll
    for (int i = 0; i < 8; ++i)
      a[i] = *(const bf16x8*)(Ap + 8192 + (wr * 128 + i * 16 + l15) * 32 + ks);
    b0 = *(const bf16x8*)(Bp + 8192 + (wc * 64 + l15) * 32 + ks);
    b1 = *(const bf16x8*)(Bp + 8192 + (wc * 64 + 16 + l15) * 32 + ks);
    gll16(ag0 + kof + 32, lds + nxt + 8192 + t8);
    gll16(ag1 + kof + 32, lds + nxt + 8192 + 4096 + t8);
    SBAR();
    __builtin_amdgcn_s_setprio(1);
#pragma unroll
    for (int i = 0; i < 8; ++i) {
      acc[i][0] = __builtin_amdgcn_mfma_f32_16x16x32_bf16(a[i], b0, acc[i][0], 0, 0, 0);
      acc[i][1] = __builtin_amdgcn_mfma_f32_16x16x32_bf16(a[i], b1, acc[i][1], 0, 0, 0);
    }
    __builtin_amdgcn_s_setprio(0);
    SBAR();
    // ---- phase 4: kh1 x Nfrags {2,3} ----
    b0 = *(const bf16x8*)(Bp + 8192 + (wc * 64 + 32 + l15) * 32 + ks);
    b1 = *(const bf16x8*)(Bp + 8192 + (wc * 64 + 48 + l15) * 32 + ks);
    gll16(bg0 + kof + 32, lds + 32768 + nxt + 8192 + t8);
    gll16(bg1 + kof + 32, lds + 32768 + nxt + 8192 + 4096 + t8);
    asm volatile("s_waitcnt vmcnt(4)" ::: "memory");
    SBAR();
    __builtin_amdgcn_s_setprio(1);
#pragma unroll
    for (int i = 0; i < 8; ++i) {
      acc[i][2] = __builtin_amdgcn_mfma_f32_16x16x32_bf16(a[i], b0, acc[i][2], 0, 0, 0);
      acc[i][3] = __builtin_amdgcn_mfma_f32_16x16x32_bf16(a[i], b1, acc[i][3], 0, 0, 0);
    }
    __builtin_amdgcn_s_setprio(0);
    SBAR();
  }
  asm volatile("s_waitcnt vmcnt(0)" ::: "memory");
  const int r0 = m0 + wr * 128 + l4 * 4;
  if (MODE == 0) {
    const int c0 = n0 + wc * 64 + l15;
#pragma unroll
    for (int i = 0; i < 8; ++i)
#pragma unroll
      for (int j = 0; j < 4; ++j)
#pragma unroll
        for (int r = 0; r < 4; ++r)
          C[(size_t)(r0 + i * 16 + r) * N + c0 + j * 16] = f2bf(acc[i][j][r]);
  } else {
    const int nc = N >> 1;
    const int c0 = (n0 >> 1) + wc * 32 + l15;
#pragma unroll
    for (int i = 0; i < 8; ++i)
#pragma unroll
      for (int p = 0; p < 2; ++p)
#pragma unroll
        for (int r = 0; r < 4; ++r) {
          float v = acc[i][2 * p][r];
          float sv = v / (1.0f + __expf(-v));
          C[(size_t)(r0 + i * 16 + r) * nc + c0 + p * 16] = f2bf(sv * acc[i][2 * p + 1][r]);
        }
  }
}

// ---------------- bf16 MFMA GEMM, 64x128 tile, BK=64 3-DEEP counted-vmcnt + T1 + T2 ----------------
// MODE 2: C fp32 = A.W^T + R
// MODE 4: Cout fp32 and Cout2 bf16
// MODE 5: Cout fp32 = R + R2 * sigmoid(A.W^T + bias[col])
template <int MODE>
__global__ __launch_bounds__(256, 2) void mgemm64(const unsigned short* __restrict__ A,
                                                  const unsigned short* __restrict__ W,
                                                  const float* __restrict__ R,
                                                  const float* __restrict__ R2,
                                                  const float* __restrict__ bias,
                                                  void* __restrict__ Cout,
                                                  void* __restrict__ Cout2,
                                                  int M, int N, int K) {
  __shared__ unsigned short As[3][2][2048];  // [buf][khalf][64 rows x 32 k]  24 KB
  __shared__ unsigned short Bs[3][2][4096];  // [buf][khalf][128 rows x 32 k] 48 KB
  const int t = threadIdx.x;
  const int lane = t & 63;
  const int wave = t >> 6;
  const int wr = wave >> 1, wc = wave & 1;
  // T1 XCD swizzle (nwg = 512, %8 == 0)
  const int gx = gridDim.x;
  const int nwg = gx * gridDim.y;
  const int id = blockIdx.y * gx + blockIdx.x;
  const int swz = (id & 7) * (nwg >> 3) + (id >> 3);
  const int m0 = (swz / gx) * 64, n0 = (swz % gx) * 128;
  f32x4 acc[2][4] = {};
  const int srow = t >> 2;
  const int sch = (((t & 3) ^ ((t >> 3) & 3)) * 8);  // T2 pre-swizzled source chunk
  const unsigned short* Ag = A + (size_t)(m0 + srow) * K + sch;
  const unsigned short* Wg = W + (size_t)(n0 + srow) * K + sch;
  const size_t rstep = (size_t)64 * K;
  const int frow = lane & 15;
  const int l4 = lane >> 4;
  const int fk = (l4 ^ ((frow >> 1) & 3)) * 8;  // T2 read slot (per-lane constant)
  const int t8 = t * 8;
  // prologue: steps 0 and 1 -> buf0, buf1 (6 loads each)
#pragma unroll
  for (int p = 0; p < 2; ++p) {
    const int ko = p * 64;
    gll16(Ag + ko, As[p][0] + t8);
    gll16(Ag + ko + 32, As[p][1] + t8);
    gll16(Wg + ko, Bs[p][0] + t8);
    gll16(Wg + ko + rstep, Bs[p][0] + 2048 + t8);
    gll16(Wg + ko + 32, Bs[p][1] + t8);
    gll16(Wg + ko + rstep + 32, Bs[p][1] + 2048 + t8);
  }
  const int NS = K >> 6;
  for (int s = 0; s < NS; ++s) {
    const int cur = s % 3;
    const int nxt = (s + 2) % 3;
    const int kn = (s + 2 < NS) ? (s + 2) * 64 : s * 64;  // clamp keeps counts invariant
    gll16(Ag + kn, As[nxt][0] + t8);
    gll16(Ag + kn + 32, As[nxt][1] + t8);
    gll16(Wg + kn, Bs[nxt][0] + t8);
    gll16(Wg + kn + rstep, Bs[nxt][0] + 2048 + t8);
    gll16(Wg + kn + 32, Bs[nxt][1] + t8);
    gll16(Wg + kn + rstep + 32, Bs[nxt][1] + 2048 + t8);
    asm volatile("s_waitcnt vmcnt(12)" ::: "memory");  // step-s loads landed (per wave)
    SBAR();                                            // ...and visible to all waves
#pragma unroll
    for (int kh = 0; kh < 2; ++kh) {
      bf16x8 af[2], bq[4];
#pragma unroll
      for (int i = 0; i < 2; ++i)
        af[i] = *(const bf16x8*)(As[cur][kh] + (wr * 32 + i * 16 + frow) * 32 + fk);
#pragma unroll
      for (int j = 0; j < 4; ++j)
        bq[j] = *(const bf16x8*)(Bs[cur][kh] + (wc * 64 + j * 16 + frow) * 32 + fk);
      __builtin_amdgcn_s_setprio(1);
#pragma unroll
      for (int i = 0; i < 2; ++i)
#pragma unroll
        for (int j = 0; j < 4; ++j)
          acc[i][j] = __builtin_amdgcn_mfma_f32_16x16x32_bf16(af[i], bq[j], acc[i][j], 0, 0, 0);
      __builtin_amdgcn_s_setprio(0);
    }
    SBAR();  // readers of buf[cur] done before iter s+1 stages step s+3 into it
  }
  asm volatile("s_waitcnt vmcnt(0)" ::: "memory");  // drain clamped tail stages
  const int crow = wr * 32 + (lane >> 4) * 4;
  const int ccol = wc * 64 + (lane & 15);
#pragma unroll
  for (int i = 0; i < 2; ++i) {
#pragma unroll
    for (int j = 0; j < 4; ++j) {
#pragma unroll
      for (int r = 0; r < 4; ++r) {
        int row = m0 + crow + i * 16 + r;
        int col = n0 + ccol + j * 16;
        float v = acc[i][j][r];
        size_t off = (size_t)row * N + col;
        if (MODE == 2) {
          ((float*)Cout)[off] = v + R[off];
        } else if (MODE == 4) {
          ((float*)Cout)[off] = v;
          ((unsigned short*)Cout2)[off] = f2bf(v);
        } else {  // MODE 5
          float g = v + bias[col];
          float sg = 1.0f / (1.0f + __expf(-g));
          ((float*)Cout)[off] = R[off] + R2[off] * sg;
        }
      }
    }
  }
}

// ---------------- MFMA flash attention (KV-split) + CONCURRENT weight casts ----------------
// R13 proved mattn (latency-bound, ~10% HBM) absorbs cast traffic ~free. This round
// extends: out_w, w3, gate_w casts also ride here (their consumers all run later).
//   bx <  40          : attention (decode unchanged)
//   bx in [40,296)    : w12 interleave-cast rows (bx-40)*32+by
//   bx in [296,488)   : cb=(bx-296)*32+by: cb<1024 out_w; cb<5120 w3; else gate_w
// Cast writes (woutb@0, w3b@41.9M, wgateb@50.3M, w12b@58.7M) are disjoint from attn
// reads (>=83.9M) and writes (opart/lpart <= 38.8M).
__global__ __launch_bounds__(256, 3) void mattn(const unsigned short* __restrict__ qb,
                                                const unsigned short* __restrict__ kb,
                                                const unsigned short* __restrict__ vtb,
                                                unsigned short* __restrict__ opart,
                                                float* __restrict__ lpart,
                                                const float* __restrict__ w12,
                                                unsigned short* __restrict__ w12b,
                                                const float* __restrict__ out_w,
                                                unsigned short* __restrict__ woutb,
                                                const float* __restrict__ w3,
                                                unsigned short* __restrict__ w3b,
                                                const float* __restrict__ gate_w,
                                                unsigned short* __restrict__ wgateb) {
  __shared__ unsigned short Ks[2][4096];   // dbuf 64 x 64 (8 KB each)
  __shared__ unsigned short Vts[2][4096];  // dbuf 64 d x 64 s (8 KB each)
  __shared__ unsigned short Ps[4 * 16 * 72];
  const int t = threadIdx.x;
  if (blockIdx.x >= 296) {
    // relocated weight casts (consumers run after this launch)
    const int cb = (blockIdx.x - 296) * 32 + blockIdx.y;  // 0..6143
    const float* in;
    unsigned short* out;
    int i;
    if (cb < 1024) {
      in = out_w; out = woutb; i = cb * 256 + t;
    } else if (cb < 5120) {
      in = w3; out = w3b; i = (cb - 1024) * 256 + t;
    } else {
      in = gate_w; out = wgateb; i = (cb - 5120) * 256 + t;
    }
    float4 v = ((const float4*)in)[i];
    ushort4 o;
    o.x = f2bf(v.x); o.y = f2bf(v.y); o.z = f2bf(v.z); o.w = f2bf(v.w);
    ((ushort4*)out)[i] = o;
    return;
  }
  if (blockIdx.x >= 40) {
    // w12 interleave-cast: 16-row groups of W1/W2 alternating (8192 rows total)
    const int r = (blockIdx.x - 40) * 32 + blockIdx.y;
    const int g = r >> 5, u = r & 31;
    const int src = ((u < 16) ? 0 : 4096) + g * 16 + (u & 15);
    float4 v = ((const float4*)(w12 + (size_t)src * 1024))[t];
    ushort4 o;
    o.x = f2bf(v.x); o.y = f2bf(v.y); o.z = f2bf(v.z); o.w = f2bf(v.w);
    ((ushort4*)(w12b + (size_t)r * 1024))[t] = o;
    return;
  }
  // decode (qt, split) from flat index; heavy splits dispatch first
  const int bidx = 39 - blockIdx.x;
  int qt, s;
  if (bidx < 4)       { qt = bidx;                  s = 0; }
  else if (bidx < 12) { qt = 4 + ((bidx - 4) >> 1); s = (bidx - 4) & 1; }
  else if (bidx < 24) { int u = bidx - 12; int q3 = u / 3; qt = 8 + q3; s = u - 3 * q3; }
  else                { qt = 12 + ((bidx - 24) >> 2); s = (bidx - 24) & 3; }
  const int nt = 2 * qt + 2;
  const int kt0 = s * 8;
  const int kt1 = (kt0 + 8 < nt) ? kt0 + 8 : nt;
  const int bh = blockIdx.y;
  const int lane = t & 63, w = t >> 6;
  const int l15 = lane & 15, l4 = lane >> 4;
  const unsigned short* qbase = qb + ((size_t)bh * Sc + qt * 128) * 64;
  const unsigned short* kbase = kb + (size_t)bh * Sc * 64;
  const unsigned short* vbase = vtb + (size_t)bh * 64 * Sc;
  // Q direct to registers (coalesced 16B/lane; no LDS round-trip)
  bf16x8 qf[2][2];
#pragma unroll
  for (int ch = 0; ch < 2; ++ch)
#pragma unroll
    for (int kc = 0; kc < 2; ++kc)
      qf[ch][kc] = *(const bf16x8*)(qbase + (size_t)(ch * 64 + w * 16 + l15) * 64 +
                                    (kc * 4 + l4) * 8);
  // K/V staging pattern: thread t -> row t>>3, chunk-swizzled slot
  const int sr = t >> 3;
  const int scg = (t & 7) ^ (sr & 7);
  // prologue: K(kt0) (2), V(kt0) (2) -> buf 0
  gll16(kbase + (size_t)(kt0 * 64 + sr) * 64 + scg * 8, Ks[0] + t * 8);
  gll16(kbase + (size_t)(kt0 * 64 + sr + 32) * 64 + scg * 8, Ks[0] + 2048 + t * 8);
  gll16(vbase + (size_t)sr * Sc + kt0 * 64 + scg * 8, Vts[0] + t * 8);
  gll16(vbase + (size_t)(sr + 32) * Sc + kt0 * 64 + scg * 8, Vts[0] + 2048 + t * 8);
  f32x4 oacc[2][4] = {};
  float lrow[2][4] = {};
  unsigned short* pw = Ps + w * 16 * 72;
  for (int kt = kt0; kt < kt1; ++kt) {
    const int cur = (kt - kt0) & 1;
    const int ktn = (kt + 1 < kt1) ? kt + 1 : kt;  // clamp keeps vmcnt counts invariant
    // issue next-tile K and V into buf^1 (its readers finished before last SBAR)
    gll16(kbase + (size_t)(ktn * 64 + sr) * 64 + scg * 8, Ks[cur ^ 1] + t * 8);
    gll16(kbase + (size_t)(ktn * 64 + sr + 32) * 64 + scg * 8, Ks[cur ^ 1] + 2048 + t * 8);
    gll16(vbase + (size_t)sr * Sc + ktn * 64 + scg * 8, Vts[cur ^ 1] + t * 8);
    gll16(vbase + (size_t)(sr + 32) * Sc + ktn * 64 + scg * 8, Vts[cur ^ 1] + 2048 + t * 8);
    asm volatile("s_waitcnt vmcnt(4)" ::: "memory");  // buf[cur] K+V landed
    SBAR();                                           // ...and visible to all waves
    const bool actA = (kt <= 2 * qt);
    // QK^T for both chunks, sharing kf
    f32x4 sc[2][4] = {};
#pragma unroll
    for (int kc = 0; kc < 2; ++kc) {
      bf16x8 kf[4];
#pragma unroll
      for (int j = 0; j < 4; ++j)
        kf[j] = *(const bf16x8*)(Ks[cur] + (j * 16 + l15) * 64 + (((kc * 4 + l4) ^ (l15 & 7)) * 8));
      __builtin_amdgcn_s_setprio(1);
      if (actA) {
#pragma unroll
        for (int j = 0; j < 4; ++j)
          sc[0][j] = __builtin_amdgcn_mfma_f32_16x16x32_bf16(qf[0][kc], kf[j], sc[0][j], 0, 0, 0);
      }
#pragma unroll
      for (int j = 0; j < 4; ++j)
        sc[1][j] = __builtin_amdgcn_mfma_f32_16x16x32_bf16(qf[1][kc], kf[j], sc[1][j], 0, 0, 0);
      __builtin_amdgcn_s_setprio(0);
    }
    // causal mask on the diagonal tiles (only present in the last split)
    const int rl = w * 16 + l4 * 4;
    if (kt == 2 * qt) {
#pragma unroll
      for (int j = 0; j < 4; ++j)
#pragma unroll
        for (int r = 0; r < 4; ++r)
          if (j * 16 + l15 > rl + r) sc[0][j][r] = -INFINITY;
    }
    if (kt == 2 * qt + 1) {
#pragma unroll
      for (int j = 0; j < 4; ++j)
#pragma unroll
        for (int r = 0; r < 4; ++r)
          if (j * 16 + l15 > rl + r) sc[1][j][r] = -INFINITY;
    }
    // V fragments (landed under the same vmcnt(4); same barrier covers visibility)
    bf16x8 vf[2][4];
#pragma unroll
    for (int kc = 0; kc < 2; ++kc)
#pragma unroll
      for (int j = 0; j < 4; ++j)
        vf[kc][j] = *(const bf16x8*)(Vts[cur] + (j * 16 + l15) * 64 + (((kc * 4 + l4) ^ (l15 & 7)) * 8));
    // chunk A then chunk B: exp2 -> P to LDS -> PV (no max-sub, no rescale)
#pragma unroll
    for (int ch = 0; ch < 2; ++ch) {
      if (ch == 0 && !actA) continue;
#pragma unroll
      for (int j = 0; j < 4; ++j)
#pragma unroll
        for (int r = 0; r < 4; ++r) {
          float p = exp2f(sc[ch][j][r]);
          lrow[ch][r] += p;
          pw[(l4 * 4 + r) * 72 + j * 16 + l15] = f2bf(p);
        }
      __asm__ __volatile__("s_waitcnt lgkmcnt(0)" ::: "memory");
      __builtin_amdgcn_s_setprio(1);
#pragma unroll
      for (int kc = 0; kc < 2; ++kc) {
        bf16x8 pf = *(const bf16x8*)(pw + l15 * 72 + kc * 32 + l4 * 8);
#pragma unroll
        for (int j = 0; j < 4; ++j)
          oacc[ch][j] = __builtin_amdgcn_mfma_f32_16x16x32_bf16(pf, vf[kc][j], oacc[ch][j], 0, 0, 0);
      }
      __builtin_amdgcn_s_setprio(0);
    }
    SBAR();  // all reads of Ks/Vts[cur] complete before next iteration stages into it
  }
  asm volatile("s_waitcnt vmcnt(0)" ::: "memory");  // drain clamped last-tile stages
  // partial write: unnormalized O (bf16) + row-sum l (fp32). slot within bh == bidx.
  unsigned short* opr = opart + ((size_t)(bh * 40 + bidx) * 128) * 64;
  float* lpr = lpart + (bh * 40 + bidx) * 128;
#pragma unroll
  for (int ch = 0; ch < 2; ++ch) {
#pragma unroll
    for (int r = 0; r < 4; ++r) {
      float sum = lrow[ch][r];
      sum += __shfl_xor(sum, 1);
      sum += __shfl_xor(sum, 2);
      sum += __shfl_xor(sum, 4);
      sum += __shfl_xor(sum, 8);
      const int row = ch * 64 + w * 16 + l4 * 4 + r;
      if (l15 == 0) lpr[row] = sum;
#pragma unroll
      for (int j = 0; j < 4; ++j)
        opr[(size_t)row * 64 + j * 16 + l15] = f2bf(oacc[ch][j][r]);
    }
  }
}

// ---------------- attention partial combine: out = (sum_s O_s) / (sum_s l_s) ----------------
__global__ __launch_bounds__(256) void acomb(const unsigned short* __restrict__ Op,
                                             const float* __restrict__ lp,
                                             unsigned short* __restrict__ out) {
  const int qt = blockIdx.x, bh = blockIdx.y;
  const int b = bh >> 4, h = bh & 15;
  const int ns = (qt >> 2) + 1;
  const int base = (qt < 4) ? qt
                 : (qt < 8) ? 4 + 2 * (qt - 4)
                 : (qt < 12) ? 12 + 3 * (qt - 8)
                 : 24 + 4 * (qt - 12);
  const int t = threadIdx.x;
  const int row = t >> 1, d0 = (t & 1) * 32;
  float l = 0.0f;
  float acc[32] = {};
  for (int s = 0; s < ns; ++s) {
    const int pidx = bh * 40 + base + s;
    l += lp[pidx * 128 + row];
    const unsigned short* src = Op + ((size_t)pidx * 128 + row) * 64 + d0;
#pragma unroll
    for (int i = 0; i < 4; ++i) {
      uint4 v = *(const uint4*)(src + i * 8);
      const unsigned short* e = (const unsigned short*)&v;
#pragma unroll
      for (int j = 0; j < 8; ++j) acc[i * 8 + j] += b2f(e[j]);
    }
  }
  const float inv = 1.0f / l;
  unsigned short* dst = out + ((size_t)(b * Sc + qt * 128 + row)) * Dc + h * 64 + d0;
#pragma unroll
  for (int i = 0; i < 8; ++i) {
    ushort4 o;
    o.x = f2bf(acc[i * 4 + 0] * inv); o.y = f2bf(acc[i * 4 + 1] * inv);
    o.z = f2bf(acc[i * 4 + 2] * inv); o.w = f2bf(acc[i * 4 + 3] * inv);
    ((ushort4*)dst)[i] = o;
  }
}

extern "C" void kernel_launch(void* const* d_in, const int* in_sizes, int n_in,
                              void* d_out, int out_size, void* d_ws, size_t ws_size,
                              hipStream_t stream) {
  const float* x        = (const float*)d_in[0];
  const float* qkv_w    = (const float*)d_in[2];
  const float* out_w    = (const float*)d_in[3];
  const float* gate_w   = (const float*)d_in[4];
  const float* gate_b   = (const float*)d_in[5];
  const float* w12      = (const float*)d_in[6];
  const float* w3       = (const float*)d_in[7];
  const float* hh_vs    = (const float*)d_in[8];
  const float* inv_freq = (const float*)d_in[9];
  const float* rope_pos = (const float*)d_in[10];
  char* ws = (char*)d_ws;
  // lifetime-based slots (bytes). R13b: out_w/w3/gate_w casts moved into the mattn
  // launch (consumers mgemm64<4>/<2>/<5> all run after it); their targets
  // (woutb@0, w3b@41.9M, wgateb@50.3M) are disjoint from all mattn-time live
  // buffers (opart/lpart <= 38.8M, qb/kb/vtb >= 83.9M, w12b@58.7M).
  unsigned short* woutb  = (unsigned short*)(ws + 0);          // 2 MiB  [mattn-cast -> outproj]
  float2*         rtab   = (float2*)(ws + 2097152);            // 512 KB [prep -> ropevt]
  unsigned short* wqkvb  = (unsigned short*)(ws + 4194304);    // 6 MiB  [prep -> qkv GEMM]
  unsigned short* attnb  = (unsigned short*)(ws + 4194304);    // 8 MiB  [acomb -> outproj]
  float*          lpart  = (float*)(ws + 12582912);            // 640 KB [mattn -> acomb]
  float*          xmid   = (float*)(ws + 0);                   // 16 MiB [gate GEMM -> end]
  unsigned short* slotB  = (unsigned short*)(ws + 16777216);   // 8 MiB  xn | xn2
  unsigned short* opart  = (unsigned short*)(ws + 16777216);   // 21 MiB [mattn -> acomb]
  float*          oproj  = (float*)(ws + 25165824);            // 16 MiB [outproj -> gate GEMM]
  unsigned short* w3b    = (unsigned short*)(ws + 41943040);   // 8 MiB  [mattn-cast -> w3 GEMM]
  unsigned short* wgateb = (unsigned short*)(ws + 50331648);   // 2 MiB  [mattn-cast -> gate GEMM]
  unsigned short* qkvb   = (unsigned short*)(ws + 58720256);   // 24 MiB [qkv GEMM -> ropevt]
  unsigned short* w12b   = (unsigned short*)(ws + 58720256);   // 16 MiB [mattn-cast -> w12 GEMM]
  unsigned short* hbufb  = (unsigned short*)(ws + 75497472);   // 32 MiB [w12 GEMM -> w3 GEMM]
  unsigned short* qb     = (unsigned short*)(ws + 83886080);   // 8 MiB  [ropevt -> mattn]
  unsigned short* oprojb = (unsigned short*)(ws + 83886080);   // 8 MiB  [outproj -> gate GEMM]
  unsigned short* kb     = (unsigned short*)(ws + 92274688);   // 8 MiB
  unsigned short* vtb    = (unsigned short*)(ws + 100663296);  // 8 MiB
  float*          Qb     = (float*)(ws + 109051904);           // 16 KB
  float* outp = (float*)d_out;

  hh_kernel<<<1, 64, 0, stream>>>(hh_vs, Qb);
  prep_kernel<<<5632, 256, 0, stream>>>(qkv_w, rope_pos, inv_freq, Qb, x,
                                        rtab, wqkvb, slotB);
  mgemm8p<0><<<dim3(12, 16), 512, 0, stream>>>(slotB, wqkvb, qkvb, 4096, 3072, 1024);
  ropevt_kernel<<<3072, 256, 0, stream>>>(qkvb, rtab, qb, kb, vtb);
  mattn<<<dim3(488, 32), 256, 0, stream>>>(qb, kb, vtb, opart, lpart, w12, w12b,
                                           out_w, woutb, w3, w3b, gate_w, wgateb);
  acomb<<<dim3(16, 32), 256, 0, stream>>>(opart, lpart, attnb);
  mgemm64<4><<<dim3(8, 64), 256, 0, stream>>>(attnb, woutb, nullptr, nullptr, nullptr,
                                              oproj, oprojb, 4096, 1024, 1024);
  mgemm64<5><<<dim3(8, 64), 256, 0, stream>>>(oprojb, wgateb, x, oproj, gate_b,
                                              xmid, nullptr, 4096, 1024, 1024);
  rmsnorm_bf16_kernel<<<4096, 256, 0, stream>>>(xmid, slotB);
  mgemm8p<1><<<dim3(32, 16), 512, 0, stream>>>(slotB, w12b, hbufb, 4096, 8192, 1024);
  mgemm64<2><<<dim3(8, 64), 256, 0, stream>>>(hbufb, w3b, xmid, nullptr, nullptr,
                                              outp, nullptr, 4096, 1024, 4096);
}

// Round 15
// 484.594 us; speedup vs baseline: 1.0158x; 1.0158x over previous
//
#include <hip/hip_runtime.h>
#include <hip/hip_bf16.h>
#include <math.h>

constexpr int Bc = 2, Sc = 2048, Dc = 1024, Hc = 16, HDc = 64;
constexpr int D3 = 3 * Dc;

typedef __bf16 bf16x8 __attribute__((ext_vector_type(8)));
typedef float f32x4 __attribute__((ext_vector_type(4)));

__device__ __forceinline__ void gll16(const void* g, void* l) {
  __builtin_amdgcn_global_load_lds((const __attribute__((address_space(1))) unsigned int*)g,
                                   (__attribute__((address_space(3))) unsigned int*)l,
                                   16, 0, 0);
}

__device__ __forceinline__ unsigned short f2bf(float v) {
  __hip_bfloat16 h = __float2bfloat16(v);
  return *(unsigned short*)&h;
}
__device__ __forceinline__ float b2f(unsigned short u) {
  unsigned v = ((unsigned)u) << 16;
  return __uint_as_float(v);
}

#define SBAR() asm volatile("s_barrier" ::: "memory")

// ---------------- Householder product Q (64x64), 1 block, 64 threads ----------------
__global__ __launch_bounds__(64) void hh_kernel(const float* __restrict__ vs,
                                                float* __restrict__ Qout) {
  __shared__ float Qm[64][65];
  __shared__ float vsh[64];
  int t = threadIdx.x;
  for (int i = 0; i < 64; ++i) Qm[i][t] = (i == t) ? 1.0f : 0.0f;
  for (int it = 0; it < 32; ++it) {
    __syncthreads();
    vsh[t] = vs[it * 64 + t];
    __syncthreads();
    float nv = 0.0f;
    for (int i = 0; i < 64; ++i) nv += vsh[i] * vsh[i];
    float c = 2.0f / (nv + 1e-8f);
    float wj = 0.0f;
    for (int i = 0; i < 64; ++i) wj += vsh[i] * Qm[i][t];
    for (int i = 0; i < 64; ++i) Qm[i][t] -= c * vsh[i] * wj;
  }
  __syncthreads();
  for (int i = 0; i < 64; ++i) Qout[i * 64 + t] = Qm[i][t];
}

// ---------------- merged weight/table prep (R13 config: all weight casts here) ----------
//   [0,256)      rtab
//   [256,512)    wqk2 (LDS-staged Qm, W read once)
//   [512,1536)   f2b qkv_w v-part
//   [1536,2560)  f2b out_w
//   [2560,6656)  f2b w3
//   [6656,7680)  f2b gate_w
__global__ __launch_bounds__(256) void prep_kernel(const float* __restrict__ qkv_w,
                                                   const float* __restrict__ out_w,
                                                   const float* __restrict__ w3,
                                                   const float* __restrict__ gate_w,
                                                   const float* __restrict__ rope_pos,
                                                   const float* __restrict__ inv_freq,
                                                   const float* __restrict__ Qm,
                                                   float2* __restrict__ rtab,
                                                   unsigned short* __restrict__ wqkvb,
                                                   unsigned short* __restrict__ woutb,
                                                   unsigned short* __restrict__ w3b,
                                                   unsigned short* __restrict__ wgateb) {
  const int blk = blockIdx.x;
  const int t = threadIdx.x;
  if (blk < 256) {
    int id = blk * 256 + t;  // 65536 = 2048*32
    int s = id >> 5, d = id & 31;
    float pos = rope_pos[s * 2 + (d >> 4)];
    float emb = pos * inv_freq[d & 15];
    rtab[id] = make_float2(cosf(emb), sinf(emb));
  } else if (blk < 512) {
    __shared__ float qs[64 * 64];  // 16 KB
    const int gid = blk - 256;     // 0..255
    const int g = gid >> 3;
    const int c = gid & 7;
    const int base = g * 64;
#pragma unroll
    for (int i = 0; i < 16; ++i) qs[t + i * 256] = Qm[t + i * 256];
    __syncthreads();
    const int tj = t & 127;
    const int rh = (t >> 7) * 32;
    const int col = c * 128 + tj;
    float acc[32] = {};
    const float* wp = qkv_w + (size_t)base * 1024 + col;
    for (int e = 0; e < 64; ++e) {
      float wv = wp[(size_t)e * 1024];
#pragma unroll
      for (int r = 0; r < 32; ++r) acc[r] += qs[(rh + r) * 64 + e] * wv;
    }
    const float sc = (base < 1024) ? 0.18033688f : 1.0f;  // 0.125 * log2(e)
#pragma unroll
    for (int r = 0; r < 32; ++r)
      wqkvb[(size_t)(base + rh + r) * 1024 + col] = f2bf(acc[r] * sc);
  } else {
    const float* in;
    unsigned short* out;
    int i;
    if (blk < 1536) {
      in = qkv_w + (size_t)2048 * 1024;
      out = wqkvb + (size_t)2048 * 1024;
      i = (blk - 512) * 256 + t;
    } else if (blk < 2560) {
      in = out_w; out = woutb;
      i = (blk - 1536) * 256 + t;
    } else if (blk < 6656) {
      in = w3; out = w3b;
      i = (blk - 2560) * 256 + t;
    } else {
      in = gate_w; out = wgateb;
      i = (blk - 6656) * 256 + t;
    }
    float4 v = ((const float4*)in)[i];
    ushort4 o;
    o.x = f2bf(v.x); o.y = f2bf(v.y); o.z = f2bf(v.z); o.w = f2bf(v.w);
    ((ushort4*)out)[i] = o;
  }
}

// ---------------- RMSNorm ----------------
__device__ __forceinline__ void rms_body(const float* __restrict__ in,
                                         unsigned short* __restrict__ out, int row, int t) {
  const float4* x4 = (const float4*)(in + (size_t)row * Dc);
  float4 v = x4[t];
  float s = v.x * v.x + v.y * v.y + v.z * v.z + v.w * v.w;
#pragma unroll
  for (int off = 1; off < 64; off <<= 1) s += __shfl_xor(s, off);
  __shared__ float wsum[4];
  if ((t & 63) == 0) wsum[t >> 6] = s;
  __syncthreads();
  float tot = wsum[0] + wsum[1] + wsum[2] + wsum[3];
  float r = rsqrtf(tot * (1.0f / Dc) + 1.1920928955078125e-07f);
  ushort4 o;
  o.x = f2bf(v.x * r); o.y = f2bf(v.y * r); o.z = f2bf(v.z * r); o.w = f2bf(v.w * r);
  ((ushort4*)(out + (size_t)row * Dc))[t] = o;
}

__global__ __launch_bounds__(256) void rmsnorm_bf16_kernel(const float* __restrict__ in,
                                                           unsigned short* __restrict__ out) {
  rms_body(in, out, blockIdx.x, threadIdx.x);
}

// ---------------- merged RoPE-rotate + V-transpose (both read qkvb) ----------------
__global__ __launch_bounds__(256) void ropevt_kernel(const unsigned short* __restrict__ qkv,
                                                     const float2* __restrict__ tab,
                                                     unsigned short* __restrict__ qb,
                                                     unsigned short* __restrict__ kb,
                                                     unsigned short* __restrict__ vtb) {
  __shared__ unsigned short tile[64 * 72];
  const int blk = blockIdx.x;
  const int t = threadIdx.x;
  if (blk < 2048) {
    int gid = blk * 64 + (t >> 2);
    int sub = t & 3;
    int h = gid & 15;
    int which = (gid >> 4) & 1;
    int tok = gid >> 5;
    int s = tok & (Sc - 1), b = tok >> 11;
    const unsigned short* src = qkv + (size_t)tok * D3 + which * Dc + h * 64 + sub * 8;
    uint4 lov = *(const uint4*)src;
    uint4 hiv = *(const uint4*)(src + 32);
    const unsigned short* lp = (const unsigned short*)&lov;
    const unsigned short* hp = (const unsigned short*)&hiv;
    unsigned short olo[8], ohi[8];
    const float2* tp = tab + s * 32 + sub * 8;
#pragma unroll
    for (int i = 0; i < 8; ++i) {
      float2 cs = tp[i];
      float lo = b2f(lp[i]), hi = b2f(hp[i]);
      olo[i] = f2bf(lo * cs.x - hi * cs.y);
      ohi[i] = f2bf(hi * cs.x + lo * cs.y);
    }
    unsigned short* dst = (which ? kb : qb) + ((size_t)((b * Hc + h) * Sc + s)) * 64 + sub * 8;
    *(uint4*)dst = *(uint4*)olo;
    *(uint4*)(dst + 32) = *(uint4*)ohi;
  } else {
    int v = blk - 2048;
    int st = v & 31;
    int bh = v >> 5;
    int b = bh >> 4, h = bh & 15;
    int srow = t >> 2, c16 = (t & 3) * 16;
    const unsigned short* src =
        qkv + (size_t)(b * Sc + st * 64 + srow) * D3 + 2 * Dc + h * 64 + c16;
    uint4 a0 = *(const uint4*)src;
    uint4 a1 = *(const uint4*)(src + 8);
    *(uint4*)(tile + srow * 72 + c16) = a0;
    *(uint4*)(tile + srow * 72 + c16 + 8) = a1;
    __syncthreads();
    int d = t >> 2, sch = (t & 3) * 16;
    unsigned short tmp[16];
#pragma unroll
    for (int i = 0; i < 16; ++i) tmp[i] = tile[(sch + i) * 72 + d];
    unsigned short* dst = vtb + ((size_t)(bh * 64 + d)) * Sc + st * 64 + sch;
    *(uint4*)dst = *(uint4*)tmp;
    *(uint4*)(dst + 8) = *(uint4*)(tmp + 8);
  }
}

// ---------------- 256x256 8-phase bf16 MFMA GEMM (T1+T2+T3+T4+T5) ----------------
// At/above the m248-measured structure ceiling for K=1024 (910 vs 848 TF) -- unchanged.
// MODE 0: C[m][n] = f2bf(acc)             (stride N)
// MODE 1: B is w12-interleaved; C[m][col] = silu(x1)*x2, stride N/2.
template <int MODE>
__global__ __launch_bounds__(512, 1) void mgemm8p(const unsigned short* __restrict__ A,
                                                  const unsigned short* __restrict__ B,
                                                  unsigned short* __restrict__ C,
                                                  int M, int N, int K) {
  __shared__ unsigned short lds[65536];
  const int t = threadIdx.x;
  const int lane = t & 63;
  const int wave = t >> 6;
  const int wr = wave >> 2, wc = wave & 3;
  const int l15 = lane & 15, l4 = lane >> 4;
  const int gx = gridDim.x;
  const int nwg = gx * gridDim.y;
  const int id = blockIdx.y * gx + blockIdx.x;
  const int swz = (id & 7) * (nwg >> 3) + (id >> 3);
  const int m0 = (swz / gx) * 256;
  const int n0 = (swz % gx) * 256;
  const int NT = K >> 6;
  const int sko = (((t & 3) ^ ((t >> 3) & 3)) * 8);
  const unsigned short* ag0 = A + (size_t)(m0 + (t >> 2)) * K + sko;
  const unsigned short* ag1 = ag0 + (size_t)128 * K;
  const unsigned short* bg0 = B + (size_t)(n0 + (t >> 2)) * K + sko;
  const unsigned short* bg1 = bg0 + (size_t)128 * K;
  const int t8 = t * 8;
  const int ks = (l4 ^ ((l15 >> 1) & 3)) * 8;
  gll16(ag0, lds + t8);
  gll16(ag1, lds + 4096 + t8);
  gll16(bg0, lds + 32768 + t8);
  gll16(bg1, lds + 32768 + 4096 + t8);
  gll16(ag0 + 32, lds + 8192 + t8);
  gll16(ag1 + 32, lds + 8192 + 4096 + t8);
  gll16(bg0 + 32, lds + 32768 + 8192 + t8);
  gll16(bg1 + 32, lds + 32768 + 8192 + 4096 + t8);
  asm volatile("s_waitcnt vmcnt(4)" ::: "memory");
  SBAR();
  f32x4 acc[8][4] = {};
  for (int kt = 0; kt < NT; ++kt) {
    const int cur = (kt & 1) << 14;
    const int nxt = cur ^ 16384;
    const int kof = ((kt + 1 < NT) ? (kt + 1) : kt) << 6;
    const unsigned short* Ap = lds + cur;
    const unsigned short* Bp = lds + 32768 + cur;
    bf16x8 a[8], b0, b1;
    // ---- phase 1: kh0 x Nfrags {0,1} ----
#pragma unroll
    for (int i = 0; i < 8; ++i)
      a[i] = *(const bf16x8*)(Ap + (wr * 128 + i * 16 + l15) * 32 + ks);
    b0 = *(const bf16x8*)(Bp + (wc * 64 + l15) * 32 + ks);
    b1 = *(const bf16x8*)(Bp + (wc * 64 + 16 + l15) * 32 + ks);
    gll16(ag0 + kof, lds + nxt + t8);
    gll16(ag1 + kof, lds + nxt + 4096 + t8);
    SBAR();
    __builtin_amdgcn_s_setprio(1);
#pragma unroll
    for (int i = 0; i < 8; ++i) {
      acc[i][0] = __builtin_amdgcn_mfma_f32_16x16x32_bf16(a[i], b0, acc[i][0], 0, 0, 0);
      acc[i][1] = __builtin_amdgcn_mfma_f32_16x16x32_bf16(a[i], b1, acc[i][1], 0, 0, 0);
    }
    __builtin_amdgcn_s_setprio(0);
    SBAR();
    // ---- phase 2: kh0 x Nfrags {2,3} ----
    b0 = *(const bf16x8*)(Bp + (wc * 64 + 32 + l15) * 32 + ks);
    b1 = *(const bf16x8*)(Bp + (wc * 64 + 48 + l15) * 32 + ks);
    gll16(bg0 + kof, lds + 32768 + nxt + t8);
    gll16(bg1 + kof, lds + 32768 + nxt + 4096 + t8);
    asm volatile("s_waitcnt vmcnt(4)" ::: "memory");
    SBAR();
    __builtin_amdgcn_s_setprio(1);
#pragma unroll
    for (int i = 0; i < 8; ++i) {
      acc[i][2] = __builtin_amdgcn_mfma_f32_16x16x32_bf16(a[i], b0, acc[i][2], 0, 0, 0);
      acc[i][3] = __builtin_amdgcn_mfma_f32_16x16x32_bf16(a[i], b1, acc[i][3], 0, 0, 0);
    }
    __builtin_amdgcn_s_setprio(0);
    SBAR();
    // ---- phase 3: kh1 x Nfrags {0,1} ----
#pragma unroll
    for (int i = 0; i < 8; ++i)
      a[i] = *(const bf16x8*)(Ap + 8192 + (wr * 128 + i * 16 + l15) * 32 + ks);
    b0 = *(const bf16x8*)(Bp + 8192 + (wc * 64 + l15) * 32 + ks);
    b1 = *(const bf16x8*)(Bp + 8192 + (wc * 64 + 16 + l15) * 32 + ks);
    gll16(ag0 + kof + 32, lds + nxt + 8192 + t8);
    gll16(ag1 + kof + 32, lds + nxt + 8192 + 4096 + t8);
    SBAR();
    __builtin_amdgcn_s_setprio(1);
#pragma unroll
    for (int i = 0; i < 8; ++i) {
      acc[i][0] = __builtin_amdgcn_mfma_f32_16x16x32_bf16(a[i], b0, acc[i][0], 0, 0, 0);
      acc[i][1] = __builtin_amdgcn_mfma_f32_16x16x32_bf16(a[i], b1, acc[i][1], 0, 0, 0);
    }
    __builtin_amdgcn_s_setprio(0);
    SBAR();
    // ---- phase 4: kh1 x Nfrags {2,3} ----
    b0 = *(const bf16x8*)(Bp + 8192 + (wc * 64 + 32 + l15) * 32 + ks);
    b1 = *(const bf16x8*)(Bp + 8192 + (wc * 64 + 48 + l15) * 32 + ks);
    gll16(bg0 + kof + 32, lds + 32768 + nxt + 8192 + t8);
    gll16(bg1 + kof + 32, lds + 32768 + nxt + 8192 + 4096 + t8);
    asm volatile("s_waitcnt vmcnt(4)" ::: "memory");
    SBAR();
    __builtin_amdgcn_s_setprio(1);
#pragma unroll
    for (int i = 0; i < 8; ++i) {
      acc[i][2] = __builtin_amdgcn_mfma_f32_16x16x32_bf16(a[i], b0, acc[i][2], 0, 0, 0);
      acc[i][3] = __builtin_amdgcn_mfma_f32_16x16x32_bf16(a[i], b1, acc[i][3], 0, 0, 0);
    }
    __builtin_amdgcn_s_setprio(0);
    SBAR();
  }
  asm volatile("s_waitcnt vmcnt(0)" ::: "memory");
  const int r0 = m0 + wr * 128 + l4 * 4;
  if (MODE == 0) {
    const int c0 = n0 + wc * 64 + l15;
#pragma unroll
    for (int i = 0; i < 8; ++i)
#pragma unroll
      for (int j = 0; j < 4; ++j)
#pragma unroll
        for (int r = 0; r < 4; ++r)
          C[(size_t)(r0 + i * 16 + r) * N + c0 + j * 16] = f2bf(acc[i][j][r]);
  } else {
    const int nc = N >> 1;
    const int c0 = (n0 >> 1) + wc * 32 + l15;
#pragma unroll
    for (int i = 0; i < 8; ++i)
#pragma unroll
      for (int p = 0; p < 2; ++p)
#pragma unroll
        for (int r = 0; r < 4; ++r) {
          float v = acc[i][2 * p][r];
          float sv = v / (1.0f + __expf(-v));
          C[(size_t)(r0 + i * 16 + r) * nc + c0 + p * 16] = f2bf(sv * acc[i][2 * p + 1][r]);
        }
  }
}

// ---------------- bf16 MFMA GEMM, 64x128 tile, BK=64 3-DEEP counted-vmcnt + T1 + T2 ----------------
// MODE 2: C fp32 = A.W^T + R
// MODE 4: Cout fp32 and Cout2 bf16
// MODE 5: Cout fp32 = R + R2 * sigmoid(A.W^T + bias[col])
template <int MODE>
__global__ __launch_bounds__(256, 2) void mgemm64(const unsigned short* __restrict__ A,
                                                  const unsigned short* __restrict__ W,
                                                  const float* __restrict__ R,
                                                  const float* __restrict__ R2,
                                                  const float* __restrict__ bias,
                                                  void* __restrict__ Cout,
                                                  void* __restrict__ Cout2,
                                                  int M, int N, int K) {
  __shared__ unsigned short As[3][2][2048];  // [buf][khalf][64 rows x 32 k]  24 KB
  __shared__ unsigned short Bs[3][2][4096];  // [buf][khalf][128 rows x 32 k] 48 KB
  const int t = threadIdx.x;
  const int lane = t & 63;
  const int wave = t >> 6;
  const int wr = wave >> 1, wc = wave & 1;
  // T1 XCD swizzle (nwg = 512, %8 == 0)
  const int gx = gridDim.x;
  const int nwg = gx * gridDim.y;
  const int id = blockIdx.y * gx + blockIdx.x;
  const int swz = (id & 7) * (nwg >> 3) + (id >> 3);
  const int m0 = (swz / gx) * 64, n0 = (swz % gx) * 128;
  f32x4 acc[2][4] = {};
  const int srow = t >> 2;
  const int sch = (((t & 3) ^ ((t >> 3) & 3)) * 8);  // T2 pre-swizzled source chunk
  const unsigned short* Ag = A + (size_t)(m0 + srow) * K + sch;
  const unsigned short* Wg = W + (size_t)(n0 + srow) * K + sch;
  const size_t rstep = (size_t)64 * K;
  const int frow = lane & 15;
  const int l4 = lane >> 4;
  const int fk = (l4 ^ ((frow >> 1) & 3)) * 8;  // T2 read slot (per-lane constant)
  const int t8 = t * 8;
  // prologue: steps 0 and 1 -> buf0, buf1 (6 loads each)
#pragma unroll
  for (int p = 0; p < 2; ++p) {
    const int ko = p * 64;
    gll16(Ag + ko, As[p][0] + t8);
    gll16(Ag + ko + 32, As[p][1] + t8);
    gll16(Wg + ko, Bs[p][0] + t8);
    gll16(Wg + ko + rstep, Bs[p][0] + 2048 + t8);
    gll16(Wg + ko + 32, Bs[p][1] + t8);
    gll16(Wg + ko + rstep + 32, Bs[p][1] + 2048 + t8);
  }
  const int NS = K >> 6;
  for (int s = 0; s < NS; ++s) {
    const int cur = s % 3;
    const int nxt = (s + 2) % 3;
    const int kn = (s + 2 < NS) ? (s + 2) * 64 : s * 64;  // clamp keeps counts invariant
    gll16(Ag + kn, As[nxt][0] + t8);
    gll16(Ag + kn + 32, As[nxt][1] + t8);
    gll16(Wg + kn, Bs[nxt][0] + t8);
    gll16(Wg + kn + rstep, Bs[nxt][0] + 2048 + t8);
    gll16(Wg + kn + 32, Bs[nxt][1] + t8);
    gll16(Wg + kn + rstep + 32, Bs[nxt][1] + 2048 + t8);
    asm volatile("s_waitcnt vmcnt(12)" ::: "memory");  // step-s loads landed (per wave)
    SBAR();                                            // ...and visible to all waves
#pragma unroll
    for (int kh = 0; kh < 2; ++kh) {
      bf16x8 af[2], bq[4];
#pragma unroll
      for (int i = 0; i < 2; ++i)
        af[i] = *(const bf16x8*)(As[cur][kh] + (wr * 32 + i * 16 + frow) * 32 + fk);
#pragma unroll
      for (int j = 0; j < 4; ++j)
        bq[j] = *(const bf16x8*)(Bs[cur][kh] + (wc * 64 + j * 16 + frow) * 32 + fk);
      __builtin_amdgcn_s_setprio(1);
#pragma unroll
      for (int i = 0; i < 2; ++i)
#pragma unroll
        for (int j = 0; j < 4; ++j)
          acc[i][j] = __builtin_amdgcn_mfma_f32_16x16x32_bf16(af[i], bq[j], acc[i][j], 0, 0, 0);
      __builtin_amdgcn_s_setprio(0);
    }
    SBAR();  // readers of buf[cur] done before iter s+1 stages step s+3 into it
  }
  asm volatile("s_waitcnt vmcnt(0)" ::: "memory");  // drain clamped tail stages
  const int crow = wr * 32 + (lane >> 4) * 4;
  const int ccol = wc * 64 + (lane & 15);
#pragma unroll
  for (int i = 0; i < 2; ++i) {
#pragma unroll
    for (int j = 0; j < 4; ++j) {
#pragma unroll
      for (int r = 0; r < 4; ++r) {
        int row = m0 + crow + i * 16 + r;
        int col = n0 + ccol + j * 16;
        float v = acc[i][j][r];
        size_t off = (size_t)row * N + col;
        if (MODE == 2) {
          ((float*)Cout)[off] = v + R[off];
        } else if (MODE == 4) {
          ((float*)Cout)[off] = v;
          ((unsigned short*)Cout2)[off] = f2bf(v);
        } else {  // MODE 5
          float g = v + bias[col];
          float sg = 1.0f / (1.0f + __expf(-g));
          ((float*)Cout)[off] = R[off] + R2[off] * sg;
        }
      }
    }
  }
}

// ---------------- MFMA flash attention (KV-split) + CONCURRENT w12 cast (R13 best) ----
// bx<40 = attn (decode unchanged), bx>=40 = w12 cast row (bx-40)*32+by. Cast writes
// w12b@[58.7M,75.5M) (qkvb dead after ropevt); disjoint from attn reads (>=83.9M)
// and writes (opart/lpart <= 38.8M). R14 showed additional casts exceed mattn's
// absorption capacity -- only w12 rides here.
__global__ __launch_bounds__(256, 3) void mattn(const unsigned short* __restrict__ qb,
                                                const unsigned short* __restrict__ kb,
                                                const unsigned short* __restrict__ vtb,
                                                unsigned short* __restrict__ opart,
                                                float* __restrict__ lpart,
                                                const float* __restrict__ w12,
                                                unsigned short* __restrict__ w12b) {
  __shared__ unsigned short Ks[2][4096];   // dbuf 64 x 64 (8 KB each)
  __shared__ unsigned short Vts[2][4096];  // dbuf 64 d x 64 s (8 KB each)
  __shared__ unsigned short Ps[4 * 16 * 72];
  const int t = threadIdx.x;
  if (blockIdx.x >= 40) {
    // w12 interleave-cast: 16-row groups of W1/W2 alternating (8192 rows total)
    const int r = (blockIdx.x - 40) * 32 + blockIdx.y;
    const int g = r >> 5, u = r & 31;
    const int src = ((u < 16) ? 0 : 4096) + g * 16 + (u & 15);
    float4 v = ((const float4*)(w12 + (size_t)src * 1024))[t];
    ushort4 o;
    o.x = f2bf(v.x); o.y = f2bf(v.y); o.z = f2bf(v.z); o.w = f2bf(v.w);
    ((ushort4*)(w12b + (size_t)r * 1024))[t] = o;
    return;
  }
  // decode (qt, split) from flat index; heavy splits dispatch first
  const int bidx = 39 - blockIdx.x;
  int qt, s;
  if (bidx < 4)       { qt = bidx;                  s = 0; }
  else if (bidx < 12) { qt = 4 + ((bidx - 4) >> 1); s = (bidx - 4) & 1; }
  else if (bidx < 24) { int u = bidx - 12; int q3 = u / 3; qt = 8 + q3; s = u - 3 * q3; }
  else                { qt = 12 + ((bidx - 24) >> 2); s = (bidx - 24) & 3; }
  const int nt = 2 * qt + 2;
  const int kt0 = s * 8;
  const int kt1 = (kt0 + 8 < nt) ? kt0 + 8 : nt;
  const int bh = blockIdx.y;
  const int lane = t & 63, w = t >> 6;
  const int l15 = lane & 15, l4 = lane >> 4;
  const unsigned short* qbase = qb + ((size_t)bh * Sc + qt * 128) * 64;
  const unsigned short* kbase = kb + (size_t)bh * Sc * 64;
  const unsigned short* vbase = vtb + (size_t)bh * 64 * Sc;
  // Q direct to registers (coalesced 16B/lane; no LDS round-trip)
  bf16x8 qf[2][2];
#pragma unroll
  for (int ch = 0; ch < 2; ++ch)
#pragma unroll
    for (int kc = 0; kc < 2; ++kc)
      qf[ch][kc] = *(const bf16x8*)(qbase + (size_t)(ch * 64 + w * 16 + l15) * 64 +
                                    (kc * 4 + l4) * 8);
  // K/V staging pattern: thread t -> row t>>3, chunk-swizzled slot
  const int sr = t >> 3;
  const int scg = (t & 7) ^ (sr & 7);
  // prologue: K(kt0) (2), V(kt0) (2) -> buf 0
  gll16(kbase + (size_t)(kt0 * 64 + sr) * 64 + scg * 8, Ks[0] + t * 8);
  gll16(kbase + (size_t)(kt0 * 64 + sr + 32) * 64 + scg * 8, Ks[0] + 2048 + t * 8);
  gll16(vbase + (size_t)sr * Sc + kt0 * 64 + scg * 8, Vts[0] + t * 8);
  gll16(vbase + (size_t)(sr + 32) * Sc + kt0 * 64 + scg * 8, Vts[0] + 2048 + t * 8);
  f32x4 oacc[2][4] = {};
  float lrow[2][4] = {};
  unsigned short* pw = Ps + w * 16 * 72;
  for (int kt = kt0; kt < kt1; ++kt) {
    const int cur = (kt - kt0) & 1;
    const int ktn = (kt + 1 < kt1) ? kt + 1 : kt;  // clamp keeps vmcnt counts invariant
    // issue next-tile K and V into buf^1 (its readers finished before last SBAR)
    gll16(kbase + (size_t)(ktn * 64 + sr) * 64 + scg * 8, Ks[cur ^ 1] + t * 8);
    gll16(kbase + (size_t)(ktn * 64 + sr + 32) * 64 + scg * 8, Ks[cur ^ 1] + 2048 + t * 8);
    gll16(vbase + (size_t)sr * Sc + ktn * 64 + scg * 8, Vts[cur ^ 1] + t * 8);
    gll16(vbase + (size_t)(sr + 32) * Sc + ktn * 64 + scg * 8, Vts[cur ^ 1] + 2048 + t * 8);
    asm volatile("s_waitcnt vmcnt(4)" ::: "memory");  // buf[cur] K+V landed
    SBAR();                                           // ...and visible to all waves
    const bool actA = (kt <= 2 * qt);
    // QK^T for both chunks, sharing kf
    f32x4 sc[2][4] = {};
#pragma unroll
    for (int kc = 0; kc < 2; ++kc) {
      bf16x8 kf[4];
#pragma unroll
      for (int j = 0; j < 4; ++j)
        kf[j] = *(const bf16x8*)(Ks[cur] + (j * 16 + l15) * 64 + (((kc * 4 + l4) ^ (l15 & 7)) * 8));
      __builtin_amdgcn_s_setprio(1);
      if (actA) {
#pragma unroll
        for (int j = 0; j < 4; ++j)
          sc[0][j] = __builtin_amdgcn_mfma_f32_16x16x32_bf16(qf[0][kc], kf[j], sc[0][j], 0, 0, 0);
      }
#pragma unroll
      for (int j = 0; j < 4; ++j)
        sc[1][j] = __builtin_amdgcn_mfma_f32_16x16x32_bf16(qf[1][kc], kf[j], sc[1][j], 0, 0, 0);
      __builtin_amdgcn_s_setprio(0);
    }
    // causal mask on the diagonal tiles (only present in the last split)
    const int rl = w * 16 + l4 * 4;
    if (kt == 2 * qt) {
#pragma unroll
      for (int j = 0; j < 4; ++j)
#pragma unroll
        for (int r = 0; r < 4; ++r)
          if (j * 16 + l15 > rl + r) sc[0][j][r] = -INFINITY;
    }
    if (kt == 2 * qt + 1) {
#pragma unroll
      for (int j = 0; j < 4; ++j)
#pragma unroll
        for (int r = 0; r < 4; ++r)
          if (j * 16 + l15 > rl + r) sc[1][j][r] = -INFINITY;
    }
    // V fragments (landed under the same vmcnt(4); same barrier covers visibility)
    bf16x8 vf[2][4];
#pragma unroll
    for (int kc = 0; kc < 2; ++kc)
#pragma unroll
      for (int j = 0; j < 4; ++j)
        vf[kc][j] = *(const bf16x8*)(Vts[cur] + (j * 16 + l15) * 64 + (((kc * 4 + l4) ^ (l15 & 7)) * 8));
    // chunk A then chunk B: exp2 -> P to LDS -> PV (no max-sub, no rescale)
#pragma unroll
    for (int ch = 0; ch < 2; ++ch) {
      if (ch == 0 && !actA) continue;
#pragma unroll
      for (int j = 0; j < 4; ++j)
#pragma unroll
        for (int r = 0; r < 4; ++r) {
          float p = exp2f(sc[ch][j][r]);
          lrow[ch][r] += p;
          pw[(l4 * 4 + r) * 72 + j * 16 + l15] = f2bf(p);
        }
      __asm__ __volatile__("s_waitcnt lgkmcnt(0)" ::: "memory");
      __builtin_amdgcn_s_setprio(1);
#pragma unroll
      for (int kc = 0; kc < 2; ++kc) {
        bf16x8 pf = *(const bf16x8*)(pw + l15 * 72 + kc * 32 + l4 * 8);
#pragma unroll
        for (int j = 0; j < 4; ++j)
          oacc[ch][j] = __builtin_amdgcn_mfma_f32_16x16x32_bf16(pf, vf[kc][j], oacc[ch][j], 0, 0, 0);
      }
      __builtin_amdgcn_s_setprio(0);
    }
    SBAR();  // all reads of Ks/Vts[cur] complete before next iteration stages into it
  }
  asm volatile("s_waitcnt vmcnt(0)" ::: "memory");  // drain clamped last-tile stages
  // partial write: unnormalized O (bf16) + row-sum l (fp32). slot within bh == bidx.
  unsigned short* opr = opart + ((size_t)(bh * 40 + bidx) * 128) * 64;
  float* lpr = lpart + (bh * 40 + bidx) * 128;
#pragma unroll
  for (int ch = 0; ch < 2; ++ch) {
#pragma unroll
    for (int r = 0; r < 4; ++r) {
      float sum = lrow[ch][r];
      sum += __shfl_xor(sum, 1);
      sum += __shfl_xor(sum, 2);
      sum += __shfl_xor(sum, 4);
      sum += __shfl_xor(sum, 8);
      const int row = ch * 64 + w * 16 + l4 * 4 + r;
      if (l15 == 0) lpr[row] = sum;
#pragma unroll
      for (int j = 0; j < 4; ++j)
        opr[(size_t)row * 64 + j * 16 + l15] = f2bf(oacc[ch][j][r]);
    }
  }
}

// ---------------- attention partial combine: out = (sum_s O_s) / (sum_s l_s) ----------------
__global__ __launch_bounds__(256) void acomb(const unsigned short* __restrict__ Op,
                                             const float* __restrict__ lp,
                                             unsigned short* __restrict__ out) {
  const int qt = blockIdx.x, bh = blockIdx.y;
  const int b = bh >> 4, h = bh & 15;
  const int ns = (qt >> 2) + 1;
  const int base = (qt < 4) ? qt
                 : (qt < 8) ? 4 + 2 * (qt - 4)
                 : (qt < 12) ? 12 + 3 * (qt - 8)
                 : 24 + 4 * (qt - 12);
  const int t = threadIdx.x;
  const int row = t >> 1, d0 = (t & 1) * 32;
  float l = 0.0f;
  float acc[32] = {};
  for (int s = 0; s < ns; ++s) {
    const int pidx = bh * 40 + base + s;
    l += lp[pidx * 128 + row];
    const unsigned short* src = Op + ((size_t)pidx * 128 + row) * 64 + d0;
#pragma unroll
    for (int i = 0; i < 4; ++i) {
      uint4 v = *(const uint4*)(src + i * 8);
      const unsigned short* e = (const unsigned short*)&v;
#pragma unroll
      for (int j = 0; j < 8; ++j) acc[i * 8 + j] += b2f(e[j]);
    }
  }
  const float inv = 1.0f / l;
  unsigned short* dst = out + ((size_t)(b * Sc + qt * 128 + row)) * Dc + h * 64 + d0;
#pragma unroll
  for (int i = 0; i < 8; ++i) {
    ushort4 o;
    o.x = f2bf(acc[i * 4 + 0] * inv); o.y = f2bf(acc[i * 4 + 1] * inv);
    o.z = f2bf(acc[i * 4 + 2] * inv); o.w = f2bf(acc[i * 4 + 3] * inv);
    ((ushort4*)dst)[i] = o;
  }
}

extern "C" void kernel_launch(void* const* d_in, const int* in_sizes, int n_in,
                              void* d_out, int out_size, void* d_ws, size_t ws_size,
                              hipStream_t stream) {
  const float* x        = (const float*)d_in[0];
  const float* qkv_w    = (const float*)d_in[2];
  const float* out_w    = (const float*)d_in[3];
  const float* gate_w   = (const float*)d_in[4];
  const float* gate_b   = (const float*)d_in[5];
  const float* w12      = (const float*)d_in[6];
  const float* w3       = (const float*)d_in[7];
  const float* hh_vs    = (const float*)d_in[8];
  const float* inv_freq = (const float*)d_in[9];
  const float* rope_pos = (const float*)d_in[10];
  char* ws = (char*)d_ws;
  // lifetime-based slots (bytes) -- R13 best-measured layout.
  unsigned short* woutb  = (unsigned short*)(ws + 0);          // 2 MiB  [prep -> outproj]
  float2*         rtab   = (float2*)(ws + 2097152);            // 512 KB [prep -> ropevt]
  unsigned short* wqkvb  = (unsigned short*)(ws + 4194304);    // 6 MiB  [prep -> qkv GEMM]
  unsigned short* attnb  = (unsigned short*)(ws + 4194304);    // 8 MiB  [acomb -> outproj]
  float*          lpart  = (float*)(ws + 12582912);            // 640 KB [mattn -> acomb]
  float*          xmid   = (float*)(ws + 0);                   // 16 MiB [gate GEMM -> end]
  unsigned short* slotB  = (unsigned short*)(ws + 16777216);   // 8 MiB  xn | xn2
  unsigned short* opart  = (unsigned short*)(ws + 16777216);   // 21 MiB [mattn -> acomb]
  float*          oproj  = (float*)(ws + 25165824);            // 16 MiB [outproj -> gate GEMM]
  unsigned short* w3b    = (unsigned short*)(ws + 41943040);   // 8 MiB  [prep -> w3 GEMM]
  unsigned short* wgateb = (unsigned short*)(ws + 50331648);   // 2 MiB  [prep -> gate GEMM]
  unsigned short* qkvb   = (unsigned short*)(ws + 58720256);   // 24 MiB [qkv GEMM -> ropevt]
  unsigned short* w12b   = (unsigned short*)(ws + 58720256);   // 16 MiB [mattn-cast -> w12 GEMM]
  unsigned short* hbufb  = (unsigned short*)(ws + 75497472);   // 32 MiB [w12 GEMM -> w3 GEMM]
  unsigned short* qb     = (unsigned short*)(ws + 83886080);   // 8 MiB  [ropevt -> mattn]
  unsigned short* oprojb = (unsigned short*)(ws + 83886080);   // 8 MiB  [outproj -> gate GEMM]
  unsigned short* kb     = (unsigned short*)(ws + 92274688);   // 8 MiB
  unsigned short* vtb    = (unsigned short*)(ws + 100663296);  // 8 MiB
  float*          Qb     = (float*)(ws + 109051904);           // 16 KB
  float* outp = (float*)d_out;

  hh_kernel<<<1, 64, 0, stream>>>(hh_vs, Qb);
  prep_kernel<<<7680, 256, 0, stream>>>(qkv_w, out_w, w3, gate_w, rope_pos, inv_freq, Qb,
                                        rtab, wqkvb, woutb, w3b, wgateb);
  rmsnorm_bf16_kernel<<<4096, 256, 0, stream>>>(x, slotB);
  mgemm8p<0><<<dim3(12, 16), 512, 0, stream>>>(slotB, wqkvb, qkvb, 4096, 3072, 1024);
  ropevt_kernel<<<3072, 256, 0, stream>>>(qkvb, rtab, qb, kb, vtb);
  mattn<<<dim3(296, 32), 256, 0, stream>>>(qb, kb, vtb, opart, lpart, w12, w12b);
  acomb<<<dim3(16, 32), 256, 0, stream>>>(opart, lpart, attnb);
  mgemm64<4><<<dim3(8, 64), 256, 0, stream>>>(attnb, woutb, nullptr, nullptr, nullptr,
                                              oproj, oprojb, 4096, 1024, 1024);
  mgemm64<5><<<dim3(8, 64), 256, 0, stream>>>(oprojb, wgateb, x, oproj, gate_b,
                                              xmid, nullptr, 4096, 1024, 1024);
  rmsnorm_bf16_kernel<<<4096, 256, 0, stream>>>(xmid, slotB);
  mgemm8p<1><<<dim3(32, 16), 512, 0, stream>>>(slotB, w12b, hbufb, 4096, 8192, 1024);
  mgemm64<2><<<dim3(8, 64), 256, 0, stream>>>(hbufb, w3b, xmid, nullptr, nullptr,
                                              outp, nullptr, 4096, 1024, 4096);
}